// Round 20
// baseline (92.523 us; speedup 1.0000x reference)
//
#include <hip/hip_runtime.h>
#include <hip/hip_bf16.h>
#include <math.h>

// Trittention forward: B=2,H=8,S=192,D=64, fp32 in/out.
// scores[q,t,s] = sum_h q[h]*k1[t,h]*k2[s,h]  ==  (W @ k2^T), W = q (.) k1
// softmax over flat (t,s); z = (sum_t At v1 + sum_s As v2)/suma via marginals.
// Round 20: crack the 64-TOTAL-reg tier (arch VGPR + MFMA acc). Evidence:
// r6 = 56 arch (capped, no spill) + ~12 acc = 68 -> 16 waves; r15 = 36 + 4
// = 40 -> 61% occ. Design: 1 q/block (grid 3072), i-loop AND j-loop
// unroll 1, ONE live f32x4 acc (4 regs), no runtime-indexed reg arrays
// (As reduced per-(i,j) into LDS instead of cv[3]); (512,8) cap with
// natural need ~48 arch. LDS 51KB -> 3 blocks/CU. Spill sentinel:
// WRITE_SIZE. Falsifier: occupancy <=45% -> revert r19, declare plateau.

#define SS 192
#define DD 64
#define NT 512   // 8 waves: 2 (t) x 4 (s) wave grid, wave tile 96x48

typedef __attribute__((ext_vector_type(8))) short bf16x8;
typedef __attribute__((ext_vector_type(4))) float f32x4;

static __device__ __forceinline__ unsigned pk_bf16(float a, float b) {
    union { __hip_bfloat162 h; unsigned u; } cv;
    cv.h = __float22bfloat162_rn(float2{a, b});   // v_cvt_pk_bf16_f32 (RNE)
    return cv.u;
}

// one DPP-add step: v += v[lane ^pattern], within rows of 16 lanes
#define DPP_STEP(v, CTRL)                                                   \
    (v) += __int_as_float(__builtin_amdgcn_update_dpp(                      \
        0, __float_as_int(v), (CTRL), 0xF, 0xF, true))

static __device__ __forceinline__ float row16_sum(float v) {
    DPP_STEP(v, 0xB1);   // quad_perm [1,0,3,2]  : xor 1
    DPP_STEP(v, 0x4E);   // quad_perm [2,3,0,1]  : xor 2
    DPP_STEP(v, 0x141);  // row_half_mirror
    DPP_STEP(v, 0x140);  // row_mirror
    return v;            // all 16 lanes of the row hold the row sum
}

// ---- prepack: k2 fp32 -> bf16, stored PRE-SWIZZLED (chunk c at c^(r&7)) ----
__global__ __launch_bounds__(512) void k2_pack(const float* __restrict__ k2g,
                                               uint4* __restrict__ outp) {
    int i = blockIdx.x * 512 + threadIdx.x;   // 16B-chunk id, 0..24575
    const float4* in = (const float4*)k2g;
    float4 a = in[2 * i], b = in[2 * i + 1];
    uint4 w;
    w.x = pk_bf16(a.x, a.y);
    w.y = pk_bf16(a.z, a.w);
    w.z = pk_bf16(b.x, b.y);
    w.w = pk_bf16(b.z, b.w);
    int ih = i & 1535;                        // within-head chunk
    int r = ih >> 3, c = ih & 7;
    outp[(i & ~1535) | (r * 8 + (c ^ (r & 7)))] = w;
}

__launch_bounds__(NT, 8)
__global__ void tritt_fwd(const float* __restrict__ qg,
                          const float* __restrict__ k1g,
                          const uint4* __restrict__ k2p,   // bf16, pre-swizzled
                          const float* __restrict__ v1g,
                          const float* __restrict__ v2g,
                          float* __restrict__ zg,
                          float* __restrict__ lseg) {
    // bf16 tiles, row = 64 bf16 = 8 chunks of 16B; chunk c stored at c^(r&7).
    __shared__ uint4 k2l[SS * 8];              // 24.5 KB
    __shared__ uint4 wl[SS * 8];               // 24.5 KB
    __shared__ float At[SS];
    __shared__ float As[SS];
    __shared__ float zsh[DD];

    const int tid = threadIdx.x;
    const int bid = blockIdx.x;           // (b*H + n)*S + q
    const int head = bid / SS;
    const size_t hb = (size_t)head * SS * DD;

    // k2 staging: direct global->LDS DMA (source pre-swizzled, dest linear)
    const uint4* k2h = k2p + (size_t)head * (SS * 8);
    #pragma unroll
    for (int it = 0; it < (SS * 8) / NT; ++it) {   // 3 iters
        int f8 = tid + it * NT;
        __builtin_amdgcn_global_load_lds(
            (const __attribute__((address_space(1))) unsigned int*)(k2h + f8),
            (__attribute__((address_space(3))) unsigned int*)&k2l[f8],
            16, 0, 0);
    }

    if (tid < SS) At[tid] = 0.f;
    else if (tid < 2 * SS) As[tid - SS] = 0.f;
    else if (tid < 2 * SS + DD) zsh[tid - 2 * SS] = 0.f;

    // ---- stage W = q*k1*log2e into LDS as bf16 (swizzled) ----
    const float L2E = 1.44269504088896340736f;
    const float4* k1v = (const float4*)(k1g + hb);
    const float4* qv  = (const float4*)(qg + (size_t)bid * DD);
    {
        const int c = tid & 7;            // chunk within row: constant/thread
        float4 p0 = qv[2 * c], p1 = qv[2 * c + 1];
        p0.x *= L2E; p0.y *= L2E; p0.z *= L2E; p0.w *= L2E;
        p1.x *= L2E; p1.y *= L2E; p1.z *= L2E; p1.w *= L2E;
        #pragma unroll 1
        for (int it = 0; it < (SS * 8) / NT; ++it) {   // 3 serial iters
            int f8 = tid + it * NT;        // 16B-chunk id
            int r = f8 >> 3;
            float4 a0 = k1v[2 * f8], a1 = k1v[2 * f8 + 1];
            uint4 w;
            w.x = pk_bf16(a0.x * p0.x, a0.y * p0.y);
            w.y = pk_bf16(a0.z * p0.z, a0.w * p0.w);
            w.z = pk_bf16(a1.x * p1.x, a1.y * p1.y);
            w.w = pk_bf16(a1.z * p1.z, a1.w * p1.w);
            wl[r * 8 + (c ^ (r & 7))] = w;
        }
    }
    __syncthreads();

    // ---- fused score-GEMM + exp + marginals. Wave (wt,ws) owns 96x48. ----
    const int lane = tid & 63;
    const int wid  = tid >> 6;
    const int wt   = wid >> 2;            // 0..1
    const int ws   = wid & 3;             // 0..3
    const int lrow = lane & 15;
    const int lk   = lane >> 4;           // 0..3 (k-group)
    const int lrm  = lrow & 7;

    // Swizzle term (ks*4+lk)^lrm is i/j-independent (96,48,16 all ≡0 mod 8).
    const int sw0 = lk ^ lrm;             // ks = 0
    const int sw1 = (4 + lk) ^ lrm;       // ks = 1
    const int ab  = (wt * 96 + lrow) * 8; // A chunk base
    const int bb  = (ws * 48 + lrow) * 8; // B chunk base

    #pragma unroll 1
    for (int i = 0; i < 6; ++i) {
        bf16x8 afr0 = *(const bf16x8*)&wl[ab + i * 128 + sw0];
        bf16x8 afr1 = *(const bf16x8*)&wl[ab + i * 128 + sw1];
        f32x4 rsv = (f32x4){0.f, 0.f, 0.f, 0.f};
        #pragma unroll 1
        for (int j = 0; j < 3; ++j) {
            f32x4 acc = (f32x4){0.f, 0.f, 0.f, 0.f};
            bf16x8 b0 = *(const bf16x8*)&k2l[bb + j * 128 + sw0];
            acc = __builtin_amdgcn_mfma_f32_16x16x32_bf16(afr0, b0, acc, 0, 0, 0);
            bf16x8 b1 = *(const bf16x8*)&k2l[bb + j * 128 + sw1];
            acc = __builtin_amdgcn_mfma_f32_16x16x32_bf16(afr1, b1, acc, 0, 0, 0);
            // D mapping: col(s) = lane&15, row(t) = (lane>>4)*4 + reg.
            f32x4 pv;
            #pragma unroll
            for (int r = 0; r < 4; ++r)
                pv[r] = __builtin_amdgcn_exp2f(acc[r]);   // = exp(score)
            rsv += pv;                     // At path: per-i, across j
            // As path: reduce this (i,j) column partial now (no cv[] regs)
            float cs = (pv[0] + pv[1]) + (pv[2] + pv[3]);
            cs += __shfl_xor(cs, 16, 64);
            cs += __shfl_xor(cs, 32, 64);
            if (lane < 16)
                atomicAdd(&As[ws * 48 + j * 16 + lane], cs);
        }
        #pragma unroll
        for (int r = 0; r < 4; ++r) {
            float v = row16_sum(rsv[r]);   // DPP, all-VALU
            if (lrow == 0)
                atomicAdd(&At[wt * 96 + i * 16 + lk * 4 + r], v);
        }
    }
    __syncthreads();

    // ---- suma (redundant per-wave reduce; no extra barrier) ----
    float suma = At[lane] + At[lane + 64] + At[lane + 128];
    suma = row16_sum(suma);
    suma += __shfl_xor(suma, 16, 64);
    suma += __shfl_xor(suma, 32, 64);

    // ---- epilogue: z[d] = (sum_t At v1 + sum_s As v2) / suma ----
    const int d = lane;
    const int g = wid;                    // 0..7, each covers 24 rows
    const float* v1p = v1g + hb;
    const float* v2p = v2g + hb;
    float zp = 0.f;
    #pragma unroll 4
    for (int r = 0; r < 24; ++r) {
        int t = g * 24 + r;
        zp = fmaf(At[t], v1p[t * DD + d], zp);
        zp = fmaf(As[t], v2p[t * DD + d], zp);
    }
    atomicAdd(&zsh[d], zp);
    __syncthreads();

    if (tid < DD) zg[(size_t)bid * DD + tid] = zsh[tid] / suma;
    if (tid == 0) lseg[bid] = logf(suma);
}

extern "C" void kernel_launch(void* const* d_in, const int* in_sizes, int n_in,
                              void* d_out, int out_size, void* d_ws, size_t ws_size,
                              hipStream_t stream) {
    const float* q  = (const float*)d_in[0];
    const float* k1 = (const float*)d_in[1];
    const float* k2 = (const float*)d_in[2];
    const float* v1 = (const float*)d_in[3];
    const float* v2 = (const float*)d_in[4];
    float* out = (float*)d_out;

    const int nq = in_sizes[0] / DD;      // B*H*S = 3072
    const int nheads = nq / SS;           // 16
    float* zout   = out;
    float* lseout = out + (size_t)nq * DD;
    uint4* k2pack = (uint4*)d_ws;         // nheads*192*64 bf16 = 384 KiB

    // prepack k2 -> bf16 pre-swizzled (q-invariant; deterministic each call)
    int n8 = nheads * SS * DD / 8;        // 24576
    hipLaunchKernelGGL(k2_pack, dim3(n8 / 512), dim3(512), 0, stream, k2, k2pack);

    dim3 grid(nq), block(NT);
    hipLaunchKernelGGL(tritt_fwd, grid, block, 0, stream,
                       q, k1, (const uint4*)k2pack, v1, v2, zout, lseout);
}

// Round 21
// 56.842 us; speedup vs baseline: 1.6277x; 1.6277x over previous
//
#include <hip/hip_runtime.h>
#include <hip/hip_bf16.h>
#include <math.h>

// Trittention forward: B=2,H=8,S=192,D=64, fp32 in/out.
// scores[q,t,s] = sum_h q[h]*k1[t,h]*k2[s,h]  ==  (W @ k2^T), W = q (.) k1
// softmax over flat (t,s); z = (sum_t At v1 + sum_s As v2)/suma via marginals.
// Round 21: r20's low-reg skeleton (tier CONFIRMED: 40 VGPR -> 61% occ) +
// restored ILP (r20's miss: 1 MFMA chain + 18 cross-lane As reduces = 2.8x
// per-wave cycles). Here: j FULLY unrolled with NAMED acc0/1/2 (3 chains,
// 12 regs), each B-fragment consumed immediately (4 regs live, no bfr[24]),
// one afr live at a time, scalar colp[3] (3 regs) reduced once per j after
// the i-loop (3 reduces total), 12-exp batches. Estimate ~51 regs <= 64 cap
// (512,8); LDS 51KB -> 3 blocks/CU (24 waves). Spill sentinel: WRITE_SIZE.

#define SS 192
#define DD 64
#define NT 512   // 8 waves: 2 (t) x 4 (s) wave grid, wave tile 96x48

typedef __attribute__((ext_vector_type(8))) short bf16x8;
typedef __attribute__((ext_vector_type(4))) float f32x4;

static __device__ __forceinline__ unsigned pk_bf16(float a, float b) {
    union { __hip_bfloat162 h; unsigned u; } cv;
    cv.h = __float22bfloat162_rn(float2{a, b});   // v_cvt_pk_bf16_f32 (RNE)
    return cv.u;
}

// one DPP-add step: v += v[lane ^pattern], within rows of 16 lanes
#define DPP_STEP(v, CTRL)                                                   \
    (v) += __int_as_float(__builtin_amdgcn_update_dpp(                      \
        0, __float_as_int(v), (CTRL), 0xF, 0xF, true))

static __device__ __forceinline__ float row16_sum(float v) {
    DPP_STEP(v, 0xB1);   // quad_perm [1,0,3,2]  : xor 1
    DPP_STEP(v, 0x4E);   // quad_perm [2,3,0,1]  : xor 2
    DPP_STEP(v, 0x141);  // row_half_mirror
    DPP_STEP(v, 0x140);  // row_mirror
    return v;            // all 16 lanes of the row hold the row sum
}

// ---- prepack: k2 fp32 -> bf16, stored PRE-SWIZZLED (chunk c at c^(r&7)) ----
__global__ __launch_bounds__(512) void k2_pack(const float* __restrict__ k2g,
                                               uint4* __restrict__ outp) {
    int i = blockIdx.x * 512 + threadIdx.x;   // 16B-chunk id, 0..24575
    const float4* in = (const float4*)k2g;
    float4 a = in[2 * i], b = in[2 * i + 1];
    uint4 w;
    w.x = pk_bf16(a.x, a.y);
    w.y = pk_bf16(a.z, a.w);
    w.z = pk_bf16(b.x, b.y);
    w.w = pk_bf16(b.z, b.w);
    int ih = i & 1535;                        // within-head chunk
    int r = ih >> 3, c = ih & 7;
    outp[(i & ~1535) | (r * 8 + (c ^ (r & 7)))] = w;
}

__launch_bounds__(NT, 8)
__global__ void tritt_fwd(const float* __restrict__ qg,
                          const float* __restrict__ k1g,
                          const uint4* __restrict__ k2p,   // bf16, pre-swizzled
                          const float* __restrict__ v1g,
                          const float* __restrict__ v2g,
                          float* __restrict__ zg,
                          float* __restrict__ lseg) {
    // bf16 tiles, row = 64 bf16 = 8 chunks of 16B; chunk c stored at c^(r&7).
    __shared__ uint4 k2l[SS * 8];              // 24.5 KB
    __shared__ uint4 wl[SS * 8];               // 24.5 KB
    __shared__ float At[SS];
    __shared__ float As[SS];
    __shared__ float zsh[DD];

    const int tid = threadIdx.x;
    const int bid = blockIdx.x;           // (b*H + n)*S + q
    const int head = bid / SS;
    const size_t hb = (size_t)head * SS * DD;

    // k2 staging: direct global->LDS DMA (source pre-swizzled, dest linear)
    const uint4* k2h = k2p + (size_t)head * (SS * 8);
    #pragma unroll
    for (int it = 0; it < (SS * 8) / NT; ++it) {   // 3 iters
        int f8 = tid + it * NT;
        __builtin_amdgcn_global_load_lds(
            (const __attribute__((address_space(1))) unsigned int*)(k2h + f8),
            (__attribute__((address_space(3))) unsigned int*)&k2l[f8],
            16, 0, 0);
    }

    if (tid < SS) At[tid] = 0.f;
    else if (tid < 2 * SS) As[tid - SS] = 0.f;
    else if (tid < 2 * SS + DD) zsh[tid - 2 * SS] = 0.f;

    // ---- stage W = q*k1*log2e into LDS as bf16 (swizzled) ----
    const float L2E = 1.44269504088896340736f;
    const float4* k1v = (const float4*)(k1g + hb);
    const float4* qv  = (const float4*)(qg + (size_t)bid * DD);
    {
        const int c = tid & 7;            // chunk within row: constant/thread
        float4 p0 = qv[2 * c], p1 = qv[2 * c + 1];
        p0.x *= L2E; p0.y *= L2E; p0.z *= L2E; p0.w *= L2E;
        p1.x *= L2E; p1.y *= L2E; p1.z *= L2E; p1.w *= L2E;
        #pragma unroll 1
        for (int it = 0; it < (SS * 8) / NT; ++it) {   // 3 serial iters
            int f8 = tid + it * NT;        // 16B-chunk id
            int r = f8 >> 3;
            float4 a0 = k1v[2 * f8], a1 = k1v[2 * f8 + 1];
            uint4 w;
            w.x = pk_bf16(a0.x * p0.x, a0.y * p0.y);
            w.y = pk_bf16(a0.z * p0.z, a0.w * p0.w);
            w.z = pk_bf16(a1.x * p1.x, a1.y * p1.y);
            w.w = pk_bf16(a1.z * p1.z, a1.w * p1.w);
            wl[r * 8 + (c ^ (r & 7))] = w;
        }
    }
    __syncthreads();

    // ---- fused score-GEMM + exp + marginals. Wave (wt,ws) owns 96x48. ----
    const int lane = tid & 63;
    const int wid  = tid >> 6;
    const int wt   = wid >> 2;            // 0..1
    const int ws   = wid & 3;             // 0..3
    const int lrow = lane & 15;
    const int lk   = lane >> 4;           // 0..3 (k-group)
    const int lrm  = lrow & 7;

    // Swizzle term (ks*4+lk)^lrm is i/j-independent (96,48,16 all ≡0 mod 8).
    const int sw0 = lk ^ lrm;             // ks = 0
    const int sw1 = (4 + lk) ^ lrm;       // ks = 1
    const int ab  = (wt * 96 + lrow) * 8; // A chunk base
    const int bb  = (ws * 48 + lrow) * 8; // B chunk base

    float colp0 = 0.f, colp1 = 0.f, colp2 = 0.f;   // scalar column partials
    #pragma unroll 1
    for (int i = 0; i < 6; ++i) {
        f32x4 acc0, acc1, acc2;
        {   // ks = 0: one afr live; each B consumed immediately
            bf16x8 afr = *(const bf16x8*)&wl[ab + i * 128 + sw0];
            f32x4 z4 = (f32x4){0.f, 0.f, 0.f, 0.f};
            acc0 = __builtin_amdgcn_mfma_f32_16x16x32_bf16(
                afr, *(const bf16x8*)&k2l[bb + 0 * 128 + sw0], z4, 0, 0, 0);
            acc1 = __builtin_amdgcn_mfma_f32_16x16x32_bf16(
                afr, *(const bf16x8*)&k2l[bb + 1 * 128 + sw0], z4, 0, 0, 0);
            acc2 = __builtin_amdgcn_mfma_f32_16x16x32_bf16(
                afr, *(const bf16x8*)&k2l[bb + 2 * 128 + sw0], z4, 0, 0, 0);
        }
        {   // ks = 1
            bf16x8 afr = *(const bf16x8*)&wl[ab + i * 128 + sw1];
            acc0 = __builtin_amdgcn_mfma_f32_16x16x32_bf16(
                afr, *(const bf16x8*)&k2l[bb + 0 * 128 + sw1], acc0, 0, 0, 0);
            acc1 = __builtin_amdgcn_mfma_f32_16x16x32_bf16(
                afr, *(const bf16x8*)&k2l[bb + 1 * 128 + sw1], acc1, 0, 0, 0);
            acc2 = __builtin_amdgcn_mfma_f32_16x16x32_bf16(
                afr, *(const bf16x8*)&k2l[bb + 2 * 128 + sw1], acc2, 0, 0, 0);
        }
        // D mapping: col(s) = lane&15, row(t) = (lane>>4)*4 + reg.
        f32x4 rsv;
        {
            f32x4 pv;
            #pragma unroll
            for (int r = 0; r < 4; ++r) pv[r] = __builtin_amdgcn_exp2f(acc0[r]);
            rsv = pv;
            colp0 += (pv[0] + pv[1]) + (pv[2] + pv[3]);
        }
        {
            f32x4 pv;
            #pragma unroll
            for (int r = 0; r < 4; ++r) pv[r] = __builtin_amdgcn_exp2f(acc1[r]);
            rsv += pv;
            colp1 += (pv[0] + pv[1]) + (pv[2] + pv[3]);
        }
        {
            f32x4 pv;
            #pragma unroll
            for (int r = 0; r < 4; ++r) pv[r] = __builtin_amdgcn_exp2f(acc2[r]);
            rsv += pv;
            colp2 += (pv[0] + pv[1]) + (pv[2] + pv[3]);
        }
        #pragma unroll
        for (int r = 0; r < 4; ++r) {
            float v = row16_sum(rsv[r]);   // DPP, all-VALU
            if (lrow == 0)
                atomicAdd(&At[wt * 96 + i * 16 + lk * 4 + r], v);
        }
    }
    // As reduction: once per column block (3 total, not 18)
    {
        float v = colp0;
        v += __shfl_xor(v, 16, 64);
        v += __shfl_xor(v, 32, 64);
        if (lane < 16) atomicAdd(&As[ws * 48 + 0 * 16 + lane], v);
    }
    {
        float v = colp1;
        v += __shfl_xor(v, 16, 64);
        v += __shfl_xor(v, 32, 64);
        if (lane < 16) atomicAdd(&As[ws * 48 + 1 * 16 + lane], v);
    }
    {
        float v = colp2;
        v += __shfl_xor(v, 16, 64);
        v += __shfl_xor(v, 32, 64);
        if (lane < 16) atomicAdd(&As[ws * 48 + 2 * 16 + lane], v);
    }
    __syncthreads();

    // ---- suma (redundant per-wave reduce; no extra barrier) ----
    float suma = At[lane] + At[lane + 64] + At[lane + 128];
    suma = row16_sum(suma);
    suma += __shfl_xor(suma, 16, 64);
    suma += __shfl_xor(suma, 32, 64);

    // ---- epilogue: z[d] = (sum_t At v1 + sum_s As v2) / suma ----
    const int d = lane;
    const int g = wid;                    // 0..7, each covers 24 rows
    const float* v1p = v1g + hb;
    const float* v2p = v2g + hb;
    float zp = 0.f;
    #pragma unroll 4
    for (int r = 0; r < 24; ++r) {
        int t = g * 24 + r;
        zp = fmaf(At[t], v1p[t * DD + d], zp);
        zp = fmaf(As[t], v2p[t * DD + d], zp);
    }
    atomicAdd(&zsh[d], zp);
    __syncthreads();

    if (tid < DD) zg[(size_t)bid * DD + tid] = zsh[tid] / suma;
    if (tid == 0) lseg[bid] = logf(suma);
}

extern "C" void kernel_launch(void* const* d_in, const int* in_sizes, int n_in,
                              void* d_out, int out_size, void* d_ws, size_t ws_size,
                              hipStream_t stream) {
    const float* q  = (const float*)d_in[0];
    const float* k1 = (const float*)d_in[1];
    const float* k2 = (const float*)d_in[2];
    const float* v1 = (const float*)d_in[3];
    const float* v2 = (const float*)d_in[4];
    float* out = (float*)d_out;

    const int nq = in_sizes[0] / DD;      // B*H*S = 3072
    const int nheads = nq / SS;           // 16
    float* zout   = out;
    float* lseout = out + (size_t)nq * DD;
    uint4* k2pack = (uint4*)d_ws;         // nheads*192*64 bf16 = 384 KiB

    // prepack k2 -> bf16 pre-swizzled (q-invariant; deterministic each call)
    int n8 = nheads * SS * DD / 8;        // 24576
    hipLaunchKernelGGL(k2_pack, dim3(n8 / 512), dim3(512), 0, stream, k2, k2pack);

    dim3 grid(nq), block(NT);
    hipLaunchKernelGGL(tritt_fwd, grid, block, 0, stream,
                       q, k1, (const uint4*)k2pack, v1, v2, zout, lseout);
}